// Round 2
// baseline (6236.059 us; speedup 1.0000x reference)
//
#include <hip/hip_runtime.h>
#include <hip/hip_bf16.h>

#define THREADS 1024
#define NWAVE (THREADS / 64)

// One block per cloud, 16 waves. Each thread owns points {t, t+1024, ...}
// with coords and running min-distance in registers (statically indexed).
// Per iteration (ONE barrier):
//   dist pass + local argmax -> wave butterfly -> lane0 writes partial to
//   LDS (parity-double-buffered) -> barrier -> all threads reduce 16
//   partials -> readfirstlane(bi) -> uniform scalar load of winner coords
//   from global (L2-resident) -> next iteration.
// First-occurrence tie-break everywhere (matches np.argmax).
template<int NPT>
__global__ __launch_bounds__(THREADS, 4)
void fps_kernel(const float* __restrict__ C, int n_pts, int m,
                int* __restrict__ idx_out) {
    const int b = blockIdx.x;
    const int t = threadIdx.x;
    const float* __restrict__ P = C + (size_t)b * n_pts * 3;

    float px[NPT], py[NPT], pz[NPT], dist[NPT];
#pragma unroll
    for (int j = 0; j < NPT; ++j) {
        int g = t + j * THREADS;
        if (g < n_pts) {
            px[j] = P[3 * g + 0];
            py[j] = P[3 * g + 1];
            pz[j] = P[3 * g + 2];
            dist[j] = 1e10f;
        } else {
            px[j] = 0.f; py[j] = 0.f; pz[j] = 0.f;
            dist[j] = -1.0f;   // never wins argmax (valid dists >= 0)
        }
    }

    __shared__ float s_pv[2][NWAVE];
    __shared__ int   s_pi[2][NWAVE];

    if (t == 0) idx_out[(size_t)b * m] = 0;   // first index is always 0

    // initial center = point 0 (uniform address -> scalar load)
    float lx = P[0], ly = P[1], lz = P[2];

    const int wid = t >> 6;

    for (int it = 1; it < m; ++it) {
        const int par = it & 1;
        float bv = -2.0f;
        int   bi = 0x7fffffff;
        // distance + min update + local argmax (ascending global index:
        // strictly-greater keeps the earliest occurrence)
#pragma unroll
        for (int j = 0; j < NPT; ++j) {
            float dx = __fsub_rn(px[j], lx);
            float dy = __fsub_rn(py[j], ly);
            float dz = __fsub_rn(pz[j], lz);
            float d  = __fadd_rn(__fadd_rn(__fmul_rn(dx, dx), __fmul_rn(dy, dy)),
                                 __fmul_rn(dz, dz));
            float nd = fminf(dist[j], d);
            dist[j] = nd;
            if (nd > bv) { bv = nd; bi = t + j * THREADS; }
        }
        // wave (64-lane) butterfly argmax, tie -> smaller index
#pragma unroll
        for (int off = 1; off < 64; off <<= 1) {
            float ov = __shfl_xor(bv, off);
            int   oi = __shfl_xor(bi, off);
            if (ov > bv || (ov == bv && oi < bi)) { bv = ov; bi = oi; }
        }
        if ((t & 63) == 0) { s_pv[par][wid] = bv; s_pi[par][wid] = bi; }
        __syncthreads();
        // every thread reduces the per-wave partials (uniform LDS reads)
        bv = s_pv[par][0]; bi = s_pi[par][0];
#pragma unroll
        for (int w = 1; w < NWAVE; ++w) {
            float v = s_pv[par][w]; int i2 = s_pi[par][w];
            if (v > bv || (v == bv && i2 < bi)) { bv = v; bi = i2; }
        }
        // bi is identical across all threads; broadcast winner coords via
        // uniform (scalar) global load -- no second barrier needed.
        int sbi = __builtin_amdgcn_readfirstlane(bi);
        if (t == 0) idx_out[(size_t)b * m + it] = sbi;
        const float* __restrict__ wp = P + 3 * (size_t)sbi;
        lx = wp[0]; ly = wp[1]; lz = wp[2];
    }
}

// Gather sampled_C [batch,m,3] and sampled_F [batch,m,c] from the indices.
__global__ void gather_kernel(const float* __restrict__ C,
                              const float* __restrict__ F,
                              const int* __restrict__ idx,
                              float* __restrict__ outC,
                              float* __restrict__ outF,
                              int n_pts, int m, int c) {
    int pair = blockIdx.x;            // b*m + s
    int b = pair / m;
    int src = idx[pair];
    size_t srcbase = (size_t)b * n_pts + src;
    const float* sF = F + srcbase * (size_t)c;
    float* dF = outF + (size_t)pair * c;
    for (int i = threadIdx.x; i < c; i += blockDim.x) dF[i] = sF[i];
    if (threadIdx.x < 3)
        outC[(size_t)pair * 3 + threadIdx.x] = C[srcbase * 3 + threadIdx.x];
}

extern "C" void kernel_launch(void* const* d_in, const int* in_sizes, int n_in,
                              void* d_out, int out_size, void* d_ws, size_t ws_size,
                              hipStream_t stream) {
    const float* C = (const float*)d_in[0];
    const float* F = (const float*)d_in[1];

    int n_total = in_sizes[0] / 3;          // batch * n_pts
    int c       = in_sizes[1] / n_total;    // feature dim (128)
    int bm      = out_size / (3 + c);       // batch * m

    int batch = 8;
    if (bm % 2000 == 0) {
        int bb = bm / 2000;
        if (bb > 0 && n_total % bb == 0 && n_total / bb >= 2000) batch = bb;
    }
    int n_pts = n_total / batch;
    int m     = (n_pts < 2000) ? n_pts : 2000;

    int* idxbuf = (int*)d_ws;               // batch*m ints
    float* outC = (float*)d_out;
    float* outF = outC + (size_t)batch * m * 3;

    int npt = (n_pts + THREADS - 1) / THREADS;
#define LAUNCH_FPS(N) fps_kernel<N><<<batch, THREADS, 0, stream>>>(C, n_pts, m, idxbuf)
    if      (npt <= 8)  LAUNCH_FPS(8);
    else if (npt <= 12) LAUNCH_FPS(12);
    else if (npt <= 16) LAUNCH_FPS(16);
    else if (npt <= 20) LAUNCH_FPS(20);
    else if (npt <= 24) LAUNCH_FPS(24);
    else                LAUNCH_FPS(32);
#undef LAUNCH_FPS

    gather_kernel<<<batch * m, 128, 0, stream>>>(C, F, idxbuf, outC, outF,
                                                 n_pts, m, c);
}

// Round 3
// 4259.849 us; speedup vs baseline: 1.4639x; 1.4639x over previous
//
#include <hip/hip_runtime.h>
#include <hip/hip_bf16.h>

#define THREADS 1024
#define NWAVE (THREADS / 64)

// One block per cloud, 16 waves, 4 waves/SIMD pinned via amdgpu_waves_per_eu
// so the full per-thread state (coords + running dist, 80 floats at NPT=20)
// lives in architectural VGPRs (128 budget) with no AGPR shuffling.
//
// Per iteration (ONE barrier):
//   distance + min-update + local argmax (best j tracked with inline-const
//   cndmask) -> pack (distbits<<32)|~idx into u64 key -> 6-round wave
//   butterfly max -> lane0 writes partial key to LDS (parity buffer) ->
//   barrier -> all threads max-scan 16 keys -> readfirstlane winner idx ->
//   uniform scalar load of winner coords from global (L2-resident).
// u64 key ordering: distances >= 0 so float bits are monotone as unsigned;
// lo = ~idx makes ties pick the SMALLEST index (np.argmax first-occurrence).
template<int NPT>
__global__ __launch_bounds__(THREADS)
__attribute__((amdgpu_waves_per_eu(4, 4)))
void fps_kernel(const float* __restrict__ C, int n_pts, int m,
                int* __restrict__ idx_out) {
    const int b = blockIdx.x;
    const int t = threadIdx.x;
    const float* __restrict__ P = C + (size_t)b * n_pts * 3;

    float px[NPT], py[NPT], pz[NPT], dist[NPT];
#pragma unroll
    for (int j = 0; j < NPT; ++j) {
        int g = t + j * THREADS;
        if (g < n_pts) {
            px[j] = P[3 * g + 0];
            py[j] = P[3 * g + 1];
            pz[j] = P[3 * g + 2];
            dist[j] = 1e10f;
        } else {
            px[j] = 0.f; py[j] = 0.f; pz[j] = 0.f;
            dist[j] = -1.0f;   // sentinel: never wins (real dists >= 0)
        }
    }

    __shared__ unsigned long long s_p[2][NWAVE];

    if (t == 0) idx_out[(size_t)b * m] = 0;   // first index is always 0

    // initial center = point 0 (uniform -> scalar load)
    float lx = P[0], ly = P[1], lz = P[2];

    const int wid = t >> 6;

    for (int it = 1; it < m; ++it) {
        const int par = it & 1;
        float bv = -2.0f;
        int   bj = 0;
        // distance + min update + local argmax; ascending j with strict >
        // keeps the earliest occurrence; bj is an inline-const select.
#pragma unroll
        for (int j = 0; j < NPT; ++j) {
            float dx = __fsub_rn(px[j], lx);
            float dy = __fsub_rn(py[j], ly);
            float dz = __fsub_rn(pz[j], lz);
            float d  = __fadd_rn(__fadd_rn(__fmul_rn(dx, dx), __fmul_rn(dy, dy)),
                                 __fmul_rn(dz, dz));
            float nd = fminf(dist[j], d);
            dist[j] = nd;
            if (nd > bv) { bv = nd; bj = j; }
        }
        int bi = t + bj * THREADS;
        unsigned long long k =
            ((unsigned long long)__float_as_uint(bv) << 32) | (unsigned)(~bi);
        if (bv < 0.0f) k = 0;   // all-padded thread: must lose

        // wave (64-lane) butterfly max on the packed key
#pragma unroll
        for (int off = 1; off < 64; off <<= 1) {
            unsigned long long ok = __shfl_xor(k, off);
            if (ok > k) k = ok;
        }
        if ((t & 63) == 0) s_p[par][wid] = k;
        __syncthreads();
        // every thread max-scans the per-wave partials (uniform LDS reads)
        unsigned long long kmax = s_p[par][0];
#pragma unroll
        for (int w = 1; w < NWAVE; ++w) {
            unsigned long long v = s_p[par][w];
            if (v > kmax) kmax = v;
        }
        int sbi = __builtin_amdgcn_readfirstlane((int)~(unsigned)kmax);
        if (t == 0) idx_out[(size_t)b * m + it] = sbi;
        // winner coords: uniform (scalar) global load, L2-resident
        const float* __restrict__ wp = P + 3 * (size_t)sbi;
        lx = wp[0]; ly = wp[1]; lz = wp[2];
    }
}

// Gather sampled_C [batch,m,3] and sampled_F [batch,m,c] from the indices.
__global__ void gather_kernel(const float* __restrict__ C,
                              const float* __restrict__ F,
                              const int* __restrict__ idx,
                              float* __restrict__ outC,
                              float* __restrict__ outF,
                              int n_pts, int m, int c) {
    int pair = blockIdx.x;            // b*m + s
    int b = pair / m;
    int src = idx[pair];
    size_t srcbase = (size_t)b * n_pts + src;
    const float* sF = F + srcbase * (size_t)c;
    float* dF = outF + (size_t)pair * c;
    for (int i = threadIdx.x; i < c; i += blockDim.x) dF[i] = sF[i];
    if (threadIdx.x < 3)
        outC[(size_t)pair * 3 + threadIdx.x] = C[srcbase * 3 + threadIdx.x];
}

extern "C" void kernel_launch(void* const* d_in, const int* in_sizes, int n_in,
                              void* d_out, int out_size, void* d_ws, size_t ws_size,
                              hipStream_t stream) {
    const float* C = (const float*)d_in[0];
    const float* F = (const float*)d_in[1];

    int n_total = in_sizes[0] / 3;          // batch * n_pts
    int c       = in_sizes[1] / n_total;    // feature dim (128)
    int bm      = out_size / (3 + c);       // batch * m

    int batch = 8;
    if (bm % 2000 == 0) {
        int bb = bm / 2000;
        if (bb > 0 && n_total % bb == 0 && n_total / bb >= 2000) batch = bb;
    }
    int n_pts = n_total / batch;
    int m     = (n_pts < 2000) ? n_pts : 2000;

    int* idxbuf = (int*)d_ws;               // batch*m ints
    float* outC = (float*)d_out;
    float* outF = outC + (size_t)batch * m * 3;

    int npt = (n_pts + THREADS - 1) / THREADS;
#define LAUNCH_FPS(N) fps_kernel<N><<<batch, THREADS, 0, stream>>>(C, n_pts, m, idxbuf)
    if      (npt <= 4)  LAUNCH_FPS(4);
    else if (npt <= 8)  LAUNCH_FPS(8);
    else if (npt <= 12) LAUNCH_FPS(12);
    else if (npt <= 16) LAUNCH_FPS(16);
    else if (npt <= 20) LAUNCH_FPS(20);
    else if (npt <= 24) LAUNCH_FPS(24);
    else                LAUNCH_FPS(32);
#undef LAUNCH_FPS

    gather_kernel<<<batch * m, 128, 0, stream>>>(C, F, idxbuf, outC, outF,
                                                 n_pts, m, c);
}